// Round 4
// baseline (528.292 us; speedup 1.0000x reference)
//
#include <hip/hip_runtime.h>
#include <math.h>

typedef long long i64;
typedef short short8v __attribute__((ext_vector_type(8)));
typedef float float4v __attribute__((ext_vector_type(4)));

#define Hd 256
#define Bb 64
#define Tn 2047
#define LEAF0 1023
#define NTH 33538048LL   // B*T*H elements

__device__ __forceinline__ float frcp(float x){ return __builtin_amdgcn_rcpf(x); }
__device__ __forceinline__ float sigm(float x){ return frcp(1.0f+__expf(-x)); }
__device__ __forceinline__ float ftanh(float x){ return 1.0f - 2.0f*frcp(__expf(2.0f*x)+1.0f); }
__device__ __forceinline__ float bf2f(unsigned short s){
  union { unsigned u; float f; } v; v.u = ((unsigned)s)<<16; return v.f; }
__device__ __forceinline__ short f2bf(float f){
  union { float f; unsigned u; } v; v.f = f;
  unsigned r = v.u + 0x7FFF + ((v.u>>16)&1);
  return (short)(r>>16); }

// ---------------------------------------------------------------------------
// Pack weights to bf16 in MFMA fragment order.
// Wt2I[hhb][kt<16][nr<20][lane<64][8] : levels, K=512, cols j = strip*256 + hhb*64 + g*16 + (lane&15),
//   nr = g*5 + strip, k = kt*32 + (lane>>4)*8 + e
// Wt2L[hhb][kt<8][nr<12][lane<64][8] : leaf, K=256, nr = g*3 + strip
// ---------------------------------------------------------------------------
__global__ __launch_bounds__(256)
void wt2_kernel(const float* __restrict__ W_iou, const float* __restrict__ U_iou,
                const float* __restrict__ U_f_w,
                short* __restrict__ Wt2I, short* __restrict__ Wt2L){
  int t = blockIdx.x*256 + threadIdx.x;
  if (blockIdx.x < 320){
    int lane = t & 63, rest = t >> 6;
    int nr = rest % 20; int rest2 = rest / 20;
    int kt = rest2 & 15, hhb = rest2 >> 4;
    int g = nr/5, strip = nr - g*5;
    int j = strip*256 + hhb*64 + g*16 + (lane&15);
    int k0 = kt*32 + (lane>>4)*8;
    const float* src = (j < 768) ? (U_iou + (i64)j*512 + k0)
                                 : (U_f_w + (i64)(j-768)*512 + k0);
    short* dst = Wt2I + (i64)t*8;
    #pragma unroll
    for (int e=0;e<8;e++) dst[e] = f2bf(src[e]);
  } else {
    int t2 = t - 320*256;
    int lane = t2 & 63, rest = t2 >> 6;
    int nr = rest % 12; int rest2 = rest / 12;
    int kt = rest2 & 7, hhb = rest2 >> 3;
    int g = nr/3, strip = nr - g*3;
    int j = strip*256 + hhb*64 + g*16 + (lane&15);
    int k0 = kt*32 + (lane>>4)*8;
    const float* src = W_iou + (i64)j*256 + k0;
    short* dst = Wt2L + (i64)t2*8;
    #pragma unroll
    for (int e=0;e<8;e++) dst[e] = f2bf(src[e]);
  }
}

// Gather+sum 5 embeddings per leaf -> bf16, stored into hb's LEAF rows.
__global__ __launch_bounds__(256)
void wemb_kernel(const int* __restrict__ wordid, const float* __restrict__ emb,
                 short* __restrict__ hb){
  int id = blockIdx.x*256 + threadIdx.x;   // 65536 rows x 32 thr, 8 cols each
  int row = id >> 5, q = id & 31;
  int b = row >> 10, j = row & 1023;
  i64 n = (i64)b*Tn + LEAF0 + j;
  const int* wid = wordid + n*5;
  float s[8];
  #pragma unroll
  for (int e=0;e<8;e++) s[e] = 0.f;
  #pragma unroll
  for (int l=0;l<5;l++){
    const float* er = emb + (i64)wid[l]*Hd + q*8;
    float4 v0 = *(const float4*)(er);
    float4 v1 = *(const float4*)(er+4);
    s[0]+=v0.x; s[1]+=v0.y; s[2]+=v0.z; s[3]+=v0.w;
    s[4]+=v1.x; s[5]+=v1.y; s[6]+=v1.z; s[7]+=v1.w;
  }
  short o[8];
  #pragma unroll
  for (int e=0;e<8;e++) o[e] = f2bf(s[e]);
  *(short8v*)(hb + n*Hd + q*8) = *(short8v*)o;
}

// Leaf GEMM: M=65536, K=256, cols = 64hh x {i,o,u}. No LDS, no barriers:
// each wave loads its own A/B fragments direct from global (L1/L2-served).
// Block 64 rows x 64 hcols; wave = 32 rows x 16 hcols x 3 strips.
__global__ __launch_bounds__(512)
void leaf_gemm(const short* __restrict__ hb, const short* __restrict__ WB,
               const float* __restrict__ b_iou, const float* __restrict__ c0,
               float* __restrict__ hOut, short* __restrict__ cbb){
  const int tid = threadIdx.x;
  const int lane = tid & 63, w = tid >> 6;
  const int wm = w >> 2, wg = w & 3;
  const int m0 = blockIdx.x*64;
  const int hhb = blockIdx.y;

  float4v acc[2][3];
  #pragma unroll
  for (int mr=0;mr<2;mr++)
    #pragma unroll
    for (int s=0;s<3;s++){ float4v z = {0.f,0.f,0.f,0.f}; acc[mr][s] = z; }

  const short* gA[2];
  #pragma unroll
  for (int mr=0;mr<2;mr++){
    const int mA = m0 + wm*32 + mr*16 + (lane&15);
    const int bA = mA >> 10, jA = mA & 1023;
    gA[mr] = hb + ((i64)bA*Tn + LEAF0 + jA)*Hd + (lane>>4)*8;
  }
  const short* gB0 = WB + (i64)hhb*96*512 + (i64)(wg*3)*512 + lane*8;

  #pragma unroll 4
  for (int kt=0; kt<8; ++kt){
    short8v a0 = *(const short8v*)(gA[0] + kt*32);
    short8v a1 = *(const short8v*)(gA[1] + kt*32);
    const short* bp = gB0 + (i64)kt*12*512;
    short8v bfr[3];
    #pragma unroll
    for (int s=0;s<3;s++) bfr[s] = *(const short8v*)(bp + (i64)s*512);
    #pragma unroll
    for (int s=0;s<3;s++)
      acc[0][s] = __builtin_amdgcn_mfma_f32_16x16x32_bf16(a0, bfr[s], acc[0][s], 0, 0, 0);
    #pragma unroll
    for (int s=0;s<3;s++)
      acc[1][s] = __builtin_amdgcn_mfma_f32_16x16x32_bf16(a1, bfr[s], acc[1][s], 0, 0, 0);
  }

  const int hcol = hhb*64 + wg*16 + (lane&15);
  const float bi = b_iou[hcol], bo = b_iou[256+hcol], bu = b_iou[512+hcol];
  #pragma unroll
  for (int mr=0;mr<2;mr++){
    const int mgb = m0 + wm*32 + mr*16 + ((lane>>4)<<2);
    #pragma unroll
    for (int r=0;r<4;r++){
      const int m = mgb + r;
      const int b = m >> 10, j = m & 1023;
      const i64 n = (i64)b*Tn + LEAF0 + j;
      const float i_ = acc[mr][0][r] + bi;
      const float o_ = acc[mr][1][r] + bo;
      const float u_ = acc[mr][2][r] + bu;
      const float cn = sigm(i_)*ftanh(u_) + c0[n*Hd + hcol];
      cbb[n*Hd + hcol] = f2bf(cn);
      hOut[n*Hd + hcol] = sigm(o_)*ftanh(cn);
    }
  }
}

// Convert leaf h (fp32 in d_out) -> bf16 hb rows.
__global__ __launch_bounds__(256)
void hconv_kernel(const float* __restrict__ hOut, short* __restrict__ hb){
  int id = blockIdx.x*256 + threadIdx.x;
  i64 idx = (i64)id*8;
  int row = (int)(idx >> 8), col = (int)(idx & 255);
  int b = row >> 10, j = row & 1023;
  i64 off = ((i64)b*Tn + LEAF0 + j)*Hd + col;
  const float* src = hOut + off;
  float4 v0 = *(const float4*)src;
  float4 v1 = *(const float4*)(src+4);
  short o[8] = { f2bf(v0.x),f2bf(v0.y),f2bf(v0.z),f2bf(v0.w),
                 f2bf(v1.x),f2bf(v1.y),f2bf(v1.z),f2bf(v1.w) };
  *(short8v*)(hb + off) = *(short8v*)o;
}

// Internal level: M=64n, K=512 (children h contiguous 512 bf16), cols = 64hh x
// {i,o,u,fl,fr}. No LDS, no barriers; wave = 32 rows x 16 hcols x 5 strips.
__global__ __launch_bounds__(512)
void level_gemm(const short* __restrict__ WB,
                const float* __restrict__ b_iou, const float* __restrict__ U_f_b,
                float* __restrict__ hOut, short* __restrict__ hb, short* __restrict__ cbb,
                float* __restrict__ outRoot, int s0, int e0, int logn){
  const int tid = threadIdx.x;
  const int lane = tid & 63, w = tid >> 6;
  const int wm = w >> 2, wg = w & 3;
  const int m0 = blockIdx.x*64;
  const int hhb = blockIdx.y;
  const int nm1 = (1<<logn)-1;

  float4v acc[2][5];
  #pragma unroll
  for (int mr=0;mr<2;mr++)
    #pragma unroll
    for (int s=0;s<5;s++){ float4v z = {0.f,0.f,0.f,0.f}; acc[mr][s] = z; }

  const short* gA[2];
  #pragma unroll
  for (int mr=0;mr<2;mr++){
    const int mA = m0 + wm*32 + mr*16 + (lane&15);
    const int bA = mA >> logn, jA = mA & nm1;
    gA[mr] = hb + ((i64)bA*Tn + e0)*Hd + (i64)jA*512 + (lane>>4)*8;
  }
  const short* gB0 = WB + (i64)hhb*320*512 + (i64)(wg*5)*512 + lane*8;

  #pragma unroll 4
  for (int kt=0; kt<16; ++kt){
    short8v a0 = *(const short8v*)(gA[0] + kt*32);
    short8v a1 = *(const short8v*)(gA[1] + kt*32);
    const short* bp = gB0 + (i64)kt*20*512;
    short8v bfr[5];
    #pragma unroll
    for (int s=0;s<5;s++) bfr[s] = *(const short8v*)(bp + (i64)s*512);
    #pragma unroll
    for (int s=0;s<5;s++)
      acc[0][s] = __builtin_amdgcn_mfma_f32_16x16x32_bf16(a0, bfr[s], acc[0][s], 0, 0, 0);
    #pragma unroll
    for (int s=0;s<5;s++)
      acc[1][s] = __builtin_amdgcn_mfma_f32_16x16x32_bf16(a1, bfr[s], acc[1][s], 0, 0, 0);
  }

  const int hcol = hhb*64 + wg*16 + (lane&15);
  const float bi = b_iou[hcol], bo = b_iou[256+hcol], bu = b_iou[512+hcol];
  const float bfl = U_f_b[hcol], bfr2 = U_f_b[256+hcol];
  #pragma unroll
  for (int mr=0;mr<2;mr++){
    const int mgb = m0 + wm*32 + mr*16 + ((lane>>4)<<2);
    #pragma unroll
    for (int r=0;r<4;r++){
      const int m = mgb + r;
      const int b = m >> logn, j = m & nm1;
      const i64 base = (i64)b*Tn;
      const i64 cidx = (base + e0 + 2*j)*Hd + hcol;
      const float cl = bf2f((unsigned short)cbb[cidx]);
      const float cr = bf2f((unsigned short)cbb[cidx + Hd]);
      const float i_ = acc[mr][0][r]+bi, o_ = acc[mr][1][r]+bo, u_ = acc[mr][2][r]+bu;
      const float fl = acc[mr][3][r]+bfl, fr = acc[mr][4][r]+bfr2;
      const float cn = sigm(i_)*ftanh(u_) + sigm(fl)*cl + sigm(fr)*cr;
      const float hv = sigm(o_)*ftanh(cn);
      const i64 oidx = (base + s0 + j)*Hd + hcol;
      cbb[oidx] = f2bf(cn);
      hb[oidx]  = f2bf(hv);
      hOut[oidx] = hv;
      if (s0 == 0){
        outRoot[b*Hd + hcol] = hv;
        outRoot[Bb*Hd + b*Hd + hcol] = cn;
      }
    }
  }
}

extern "C" void kernel_launch(void* const* d_in, const int* in_sizes, int n_in,
                              void* d_out, int out_size, void* d_ws, size_t ws_size,
                              hipStream_t stream){
  const int*   wordid = (const int*)  d_in[0];
  const float* c0     = (const float*)d_in[3];
  const float* emb    = (const float*)d_in[6];
  const float* W_iou  = (const float*)d_in[7];
  const float* U_iou  = (const float*)d_in[8];
  const float* b_iou  = (const float*)d_in[9];
  const float* U_f_w  = (const float*)d_in[10];
  const float* U_f_b  = (const float*)d_in[11];

  float* hOut    = (float*)d_out;            // (B,T,H) fp32
  float* outRoot = hOut + NTH;               // root_h then root_c
  short* cbb  = (short*)d_ws;                // c  bf16 (B,T,H)
  short* hb   = cbb + NTH;                   // h  bf16 (B,T,H); leaf rows hold wemb pre-GEMM
  short* Wt2I = hb + NTH;                    // 4*16*20*64*8 = 655360 shorts
  short* Wt2L = Wt2I + 655360;               // 4*8*12*64*8  = 196608 shorts

  hipLaunchKernelGGL(wt2_kernel, dim3(416), dim3(256), 0, stream,
                     W_iou, U_iou, U_f_w, Wt2I, Wt2L);
  hipLaunchKernelGGL(wemb_kernel, dim3(8192), dim3(256), 0, stream, wordid, emb, hb);
  hipLaunchKernelGGL(leaf_gemm, dim3(1024,4), dim3(512), 0, stream,
                     hb, Wt2L, b_iou, c0, hOut, cbb);
  hipLaunchKernelGGL(hconv_kernel, dim3(8192), dim3(256), 0, stream, hOut, hb);
  for (int d = 9; d >= 0; --d){
    const int n = 1<<d, s = n-1, e = 2*n-1;
    hipLaunchKernelGGL(level_gemm, dim3(n,4), dim3(512), 0, stream,
                       Wt2I, b_iou, U_f_b, hOut, hb, cbb, outRoot, s, e, d);
  }
}

// Round 5
// 472.753 us; speedup vs baseline: 1.1175x; 1.1175x over previous
//
#include <hip/hip_runtime.h>
#include <math.h>

typedef long long i64;
typedef short short8v __attribute__((ext_vector_type(8)));
typedef float float4v __attribute__((ext_vector_type(4)));

#define Hd 256
#define Bb 64
#define Tn 2047
#define LEAF0 1023
#define NTH 33538048LL   // B*T*H elements

__device__ __forceinline__ float frcp(float x){ return __builtin_amdgcn_rcpf(x); }
__device__ __forceinline__ float sigm(float x){ return frcp(1.0f+__expf(-x)); }
__device__ __forceinline__ float ftanh(float x){ return 1.0f - 2.0f*frcp(__expf(2.0f*x)+1.0f); }
__device__ __forceinline__ float bf2f(unsigned short s){
  union { unsigned u; float f; } v; v.u = ((unsigned)s)<<16; return v.f; }
__device__ __forceinline__ short f2bf(float f){
  union { float f; unsigned u; } v; v.f = f;
  unsigned r = v.u + 0x7FFF + ((v.u>>16)&1);
  return (short)(r>>16); }

#define GL2LDS(gp, lp) __builtin_amdgcn_global_load_lds( \
  (const __attribute__((address_space(1))) void*)(gp), \
  (__attribute__((address_space(3))) void*)(lp), 16, 0, 0)

// ---------------------------------------------------------------------------
// Pack weights to bf16 in MFMA fragment order.
// Wt2I[hhb][kt<16][nr<20][lane<64][8] : levels, K=512
// Wt2L[hhb][kt<8][nr<12][lane<64][8] : leaf, K=256
// ---------------------------------------------------------------------------
__global__ __launch_bounds__(256)
void wt2_kernel(const float* __restrict__ W_iou, const float* __restrict__ U_iou,
                const float* __restrict__ U_f_w,
                short* __restrict__ Wt2I, short* __restrict__ Wt2L){
  int t = blockIdx.x*256 + threadIdx.x;
  if (blockIdx.x < 320){
    int lane = t & 63, rest = t >> 6;
    int nr = rest % 20; int rest2 = rest / 20;
    int kt = rest2 & 15, hhb = rest2 >> 4;
    int g = nr/5, strip = nr - g*5;
    int j = strip*256 + hhb*64 + g*16 + (lane&15);
    int k0 = kt*32 + (lane>>4)*8;
    const float* src = (j < 768) ? (U_iou + (i64)j*512 + k0)
                                 : (U_f_w + (i64)(j-768)*512 + k0);
    short* dst = Wt2I + (i64)t*8;
    #pragma unroll
    for (int e=0;e<8;e++) dst[e] = f2bf(src[e]);
  } else {
    int t2 = t - 320*256;
    int lane = t2 & 63, rest = t2 >> 6;
    int nr = rest % 12; int rest2 = rest / 12;
    int kt = rest2 & 7, hhb = rest2 >> 3;
    int g = nr/3, strip = nr - g*3;
    int j = strip*256 + hhb*64 + g*16 + (lane&15);
    int k0 = kt*32 + (lane>>4)*8;
    const float* src = W_iou + (i64)j*256 + k0;
    short* dst = Wt2L + (i64)t2*8;
    #pragma unroll
    for (int e=0;e<8;e++) dst[e] = f2bf(src[e]);
  }
}

// Gather+sum 5 embeddings per leaf -> bf16, stored into hb's LEAF rows.
__global__ __launch_bounds__(256)
void wemb_kernel(const int* __restrict__ wordid, const float* __restrict__ emb,
                 short* __restrict__ hb){
  int id = blockIdx.x*256 + threadIdx.x;
  int row = id >> 5, q = id & 31;
  int b = row >> 10, j = row & 1023;
  i64 n = (i64)b*Tn + LEAF0 + j;
  const int* wid = wordid + n*5;
  float s[8];
  #pragma unroll
  for (int e=0;e<8;e++) s[e] = 0.f;
  #pragma unroll
  for (int l=0;l<5;l++){
    const float* er = emb + (i64)wid[l]*Hd + q*8;
    float4 v0 = *(const float4*)(er);
    float4 v1 = *(const float4*)(er+4);
    s[0]+=v0.x; s[1]+=v0.y; s[2]+=v0.z; s[3]+=v0.w;
    s[4]+=v1.x; s[5]+=v1.y; s[6]+=v1.z; s[7]+=v1.w;
  }
  short o[8];
  #pragma unroll
  for (int e=0;e<8;e++) o[e] = f2bf(s[e]);
  *(short8v*)(hb + n*Hd + q*8) = *(short8v*)o;
}

// Convert leaf h (fp32 in d_out) -> bf16 hb rows.
__global__ __launch_bounds__(256)
void hconv_kernel(const float* __restrict__ hOut, short* __restrict__ hb){
  int id = blockIdx.x*256 + threadIdx.x;
  i64 idx = (i64)id*8;
  int row = (int)(idx >> 8), col = (int)(idx & 255);
  int b = row >> 10, j = row & 1023;
  i64 off = ((i64)b*Tn + LEAF0 + j)*Hd + col;
  const float* src = hOut + off;
  float4 v0 = *(const float4*)src;
  float4 v1 = *(const float4*)(src+4);
  short o[8] = { f2bf(v0.x),f2bf(v0.y),f2bf(v0.z),f2bf(v0.w),
                 f2bf(v1.x),f2bf(v1.y),f2bf(v1.z),f2bf(v1.w) };
  *(short8v*)(hb + off) = *(short8v*)o;
}

// ---------------------------------------------------------------------------
// Leaf GEMM, counted-vmcnt pipeline. Block 128 rows x 64 hcols x {i,o,u}.
// A: 3-deep LDS (prefetch 2 ahead), B: 2-deep LDS (prefetch 1 ahead).
// ---------------------------------------------------------------------------
__global__ __launch_bounds__(512)
void leaf_gemm(const short* __restrict__ hb, const short* __restrict__ WB,
               const float* __restrict__ b_iou, const float* __restrict__ c0,
               float* __restrict__ hOut, short* __restrict__ cbb){
  __shared__ __align__(16) short As[3][8*512];   // 24 KB
  __shared__ __align__(16) short Bs[2][12*512];  // 24 KB
  const int tid = threadIdx.x;
  const int lane = tid & 63, w = tid >> 6;
  const int wm = w >> 2, wg = w & 3;
  const int m0 = blockIdx.x*128;
  const int hhb = blockIdx.y;

  const int rA = m0 + w*16 + (lane&15);
  const int bA = rA >> 10, jA = rA & 1023;
  const short* srcA = hb + ((i64)bA*Tn + LEAF0 + jA)*Hd + (lane>>4)*8;
  const short* wbB = WB + (i64)hhb*96*512 + lane*8;

  float4v acc[4][3];
  #pragma unroll
  for (int mr=0;mr<4;mr++)
    #pragma unroll
    for (int s=0;s<3;s++){ float4v z = {0.f,0.f,0.f,0.f}; acc[mr][s] = z; }

  auto STAGEA = [&](int kts, int buf){ GL2LDS(srcA + kts*32, &As[buf][w*512]); };
  auto STAGEB = [&](int kts, int buf){
    const short* bs = wbB + (i64)kts*12*512;
    GL2LDS(bs + (i64)w*512, &Bs[buf][w*512]);
    if (w < 4) GL2LDS(bs + (i64)(w+8)*512, &Bs[buf][(w+8)*512]);
  };

  // prologue: A(0), B(0), A(1)  (order matters for vmcnt counting)
  STAGEA(0,0); STAGEB(0,0); STAGEA(1,1);

  for (int kt=0; kt<8; ++kt){
    const int abuf = kt%3, bbuf = kt&1;
    if (kt+1 < 8) STAGEB(kt+1, (kt+1)&1);
    if (kt+2 < 8) STAGEA(kt+2, (kt+2)%3);
    // wait: B(kt) + A(kt) landed; newer-than-B(kt) = A(kt+1)+B(kt+1)+A(kt+2) = SB+2
    if (kt >= 6)      asm volatile("s_waitcnt vmcnt(0)" ::: "memory");
    else if (w < 4)   asm volatile("s_waitcnt vmcnt(4)" ::: "memory");
    else              asm volatile("s_waitcnt vmcnt(3)" ::: "memory");
    __builtin_amdgcn_s_barrier();
    short8v bfr[3], afr[4];
    #pragma unroll
    for (int s=0;s<3;s++) bfr[s] = *(const short8v*)&Bs[bbuf][(wg*3+s)*512 + lane*8];
    #pragma unroll
    for (int mr=0;mr<4;mr++) afr[mr] = *(const short8v*)&As[abuf][(wm*4+mr)*512 + lane*8];
    #pragma unroll
    for (int mr=0;mr<4;mr++)
      #pragma unroll
      for (int s=0;s<3;s++)
        acc[mr][s] = __builtin_amdgcn_mfma_f32_16x16x32_bf16(afr[mr], bfr[s], acc[mr][s], 0, 0, 0);
    // drain own ds_reads before allowing next-iter overwrites
    asm volatile("s_waitcnt lgkmcnt(0)" ::: "memory");
    __builtin_amdgcn_s_barrier();
  }

  const int hcol = hhb*64 + wg*16 + (lane&15);
  const float bi = b_iou[hcol], bo = b_iou[256+hcol], bu = b_iou[512+hcol];
  #pragma unroll
  for (int mr=0;mr<4;mr++){
    const int mgb = m0 + wm*64 + mr*16 + ((lane>>4)<<2);
    #pragma unroll
    for (int r=0;r<4;r++){
      const int m = mgb + r;
      const int b = m >> 10, j = m & 1023;
      const i64 n = (i64)b*Tn + LEAF0 + j;
      const float i_ = acc[mr][0][r] + bi;
      const float o_ = acc[mr][1][r] + bo;
      const float u_ = acc[mr][2][r] + bu;
      const float cn = sigm(i_)*ftanh(u_) + c0[n*Hd + hcol];
      cbb[n*Hd + hcol] = f2bf(cn);
      hOut[n*Hd + hcol] = sigm(o_)*ftanh(cn);
    }
  }
}

// ---------------------------------------------------------------------------
// Internal level, counted-vmcnt pipeline. Block 128 rows x 64 hcols x
// {i,o,u,fl,fr}. A: 3-deep, B: 2-deep.
// ---------------------------------------------------------------------------
__global__ __launch_bounds__(512)
void level_gemm(const short* __restrict__ WB,
                const float* __restrict__ b_iou, const float* __restrict__ U_f_b,
                float* __restrict__ hOut, short* __restrict__ hb, short* __restrict__ cbb,
                float* __restrict__ outRoot, int s0, int e0, int logn){
  __shared__ __align__(16) short As[3][8*512];   // 24 KB
  __shared__ __align__(16) short Bs[2][20*512];  // 40 KB
  const int tid = threadIdx.x;
  const int lane = tid & 63, w = tid >> 6;
  const int wm = w >> 2, wg = w & 3;
  const int m0 = blockIdx.x*128;
  const int hhb = blockIdx.y;
  const int Mtot = Bb << logn;
  const int nm1 = (1<<logn)-1;

  int rA = m0 + w*16 + (lane&15); if (rA >= Mtot) rA = Mtot-1;
  const int bA = rA >> logn, jA = rA & nm1;
  const short* srcA = hb + ((i64)bA*Tn + e0)*Hd + (i64)jA*512 + (lane>>4)*8;
  const short* wbB = WB + (i64)hhb*320*512 + lane*8;

  float4v acc[4][5];
  #pragma unroll
  for (int mr=0;mr<4;mr++)
    #pragma unroll
    for (int s=0;s<5;s++){ float4v z = {0.f,0.f,0.f,0.f}; acc[mr][s] = z; }

  auto STAGEA = [&](int kts, int buf){ GL2LDS(srcA + kts*32, &As[buf][w*512]); };
  auto STAGEB = [&](int kts, int buf){
    const short* bs = wbB + (i64)kts*20*512;
    GL2LDS(bs + (i64)w*512,     &Bs[buf][w*512]);
    GL2LDS(bs + (i64)(w+8)*512, &Bs[buf][(w+8)*512]);
    if (w < 4) GL2LDS(bs + (i64)(w+16)*512, &Bs[buf][(w+16)*512]);
  };

  STAGEA(0,0); STAGEB(0,0); STAGEA(1,1);

  for (int kt=0; kt<16; ++kt){
    const int abuf = kt%3, bbuf = kt&1;
    if (kt+1 < 16) STAGEB(kt+1, (kt+1)&1);
    if (kt+2 < 16) STAGEA(kt+2, (kt+2)%3);
    if (kt >= 14)   asm volatile("s_waitcnt vmcnt(0)" ::: "memory");
    else if (w < 4) asm volatile("s_waitcnt vmcnt(5)" ::: "memory");
    else            asm volatile("s_waitcnt vmcnt(4)" ::: "memory");
    __builtin_amdgcn_s_barrier();
    short8v bfr[5], afr[4];
    #pragma unroll
    for (int s=0;s<5;s++) bfr[s] = *(const short8v*)&Bs[bbuf][(wg*5+s)*512 + lane*8];
    #pragma unroll
    for (int mr=0;mr<4;mr++) afr[mr] = *(const short8v*)&As[abuf][(wm*4+mr)*512 + lane*8];
    #pragma unroll
    for (int mr=0;mr<4;mr++)
      #pragma unroll
      for (int s=0;s<5;s++)
        acc[mr][s] = __builtin_amdgcn_mfma_f32_16x16x32_bf16(afr[mr], bfr[s], acc[mr][s], 0, 0, 0);
    asm volatile("s_waitcnt lgkmcnt(0)" ::: "memory");
    __builtin_amdgcn_s_barrier();
  }

  const int hcol = hhb*64 + wg*16 + (lane&15);
  const float bi = b_iou[hcol], bo = b_iou[256+hcol], bu = b_iou[512+hcol];
  const float bfl = U_f_b[hcol], bfr2 = U_f_b[256+hcol];
  #pragma unroll
  for (int mr=0;mr<4;mr++){
    const int mgb = m0 + wm*64 + mr*16 + ((lane>>4)<<2);
    #pragma unroll
    for (int r=0;r<4;r++){
      const int m = mgb + r;
      if (m < Mtot){
        const int b = m >> logn, j = m & nm1;
        const i64 base = (i64)b*Tn;
        const i64 cidx = (base + e0 + 2*j)*Hd + hcol;
        const float cl = bf2f((unsigned short)cbb[cidx]);
        const float cr = bf2f((unsigned short)cbb[cidx + Hd]);
        const float i_ = acc[mr][0][r]+bi, o_ = acc[mr][1][r]+bo, u_ = acc[mr][2][r]+bu;
        const float fl = acc[mr][3][r]+bfl, fr = acc[mr][4][r]+bfr2;
        const float cn = sigm(i_)*ftanh(u_) + sigm(fl)*cl + sigm(fr)*cr;
        const float hv = sigm(o_)*ftanh(cn);
        const i64 oidx = (base + s0 + j)*Hd + hcol;
        cbb[oidx] = f2bf(cn);
        hb[oidx]  = f2bf(hv);
        hOut[oidx] = hv;
        if (s0 == 0){
          outRoot[b*Hd + hcol] = hv;
          outRoot[Bb*Hd + b*Hd + hcol] = cn;
        }
      }
    }
  }
}

extern "C" void kernel_launch(void* const* d_in, const int* in_sizes, int n_in,
                              void* d_out, int out_size, void* d_ws, size_t ws_size,
                              hipStream_t stream){
  const int*   wordid = (const int*)  d_in[0];
  const float* c0     = (const float*)d_in[3];
  const float* emb    = (const float*)d_in[6];
  const float* W_iou  = (const float*)d_in[7];
  const float* U_iou  = (const float*)d_in[8];
  const float* b_iou  = (const float*)d_in[9];
  const float* U_f_w  = (const float*)d_in[10];
  const float* U_f_b  = (const float*)d_in[11];

  float* hOut    = (float*)d_out;            // (B,T,H) fp32
  float* outRoot = hOut + NTH;               // root_h then root_c
  short* cbb  = (short*)d_ws;                // c  bf16 (B,T,H)
  short* hb   = cbb + NTH;                   // h  bf16 (B,T,H); leaf rows hold wemb pre-GEMM
  short* Wt2I = hb + NTH;                    // 655360 shorts
  short* Wt2L = Wt2I + 655360;               // 196608 shorts

  hipLaunchKernelGGL(wt2_kernel, dim3(416), dim3(256), 0, stream,
                     W_iou, U_iou, U_f_w, Wt2I, Wt2L);
  hipLaunchKernelGGL(wemb_kernel, dim3(8192), dim3(256), 0, stream, wordid, emb, hb);
  hipLaunchKernelGGL(leaf_gemm, dim3(512,4), dim3(512), 0, stream,
                     hb, Wt2L, b_iou, c0, hOut, cbb);
  hipLaunchKernelGGL(hconv_kernel, dim3(8192), dim3(256), 0, stream, hOut, hb);
  for (int d = 9; d >= 0; --d){
    const int n = 1<<d, s = n-1, e = 2*n-1;
    const int bm = (64*n + 127)/128;
    hipLaunchKernelGGL(level_gemm, dim3(bm < 1 ? 1 : bm, 4), dim3(512), 0, stream,
                       Wt2I, b_iou, U_f_b, hOut, hb, cbb, outRoot, s, e, d);
  }
}

// Round 6
// 436.108 us; speedup vs baseline: 1.2114x; 1.0840x over previous
//
#include <hip/hip_runtime.h>
#include <math.h>

typedef long long i64;
typedef short short8v __attribute__((ext_vector_type(8)));
typedef float float4v __attribute__((ext_vector_type(4)));

#define Hd 256
#define Bb 64
#define Tn 2047
#define LEAF0 1023
#define NTH 33538048LL   // B*T*H elements

__device__ __forceinline__ float frcp(float x){ return __builtin_amdgcn_rcpf(x); }
__device__ __forceinline__ float sigm(float x){ return frcp(1.0f+__expf(-x)); }
__device__ __forceinline__ float ftanh(float x){ return 1.0f - 2.0f*frcp(__expf(2.0f*x)+1.0f); }
__device__ __forceinline__ float bf2f(unsigned short s){
  union { unsigned u; float f; } v; v.u = ((unsigned)s)<<16; return v.f; }
__device__ __forceinline__ short f2bf(float f){
  union { float f; unsigned u; } v; v.f = f;
  unsigned r = v.u + 0x7FFF + ((v.u>>16)&1);
  return (short)(r>>16); }

#define GL2LDS(gp, lp) __builtin_amdgcn_global_load_lds( \
  (const __attribute__((address_space(1))) void*)(gp), \
  (__attribute__((address_space(3))) void*)(lp), 16, 0, 0)

// ---------------------------------------------------------------------------
// Pack weights to bf16 in MFMA fragment order.
// Wt2I[hhb][kt<16][nr<20][lane<64][8] : levels, K=512
// Wt2L[hhb][kt<8][nr<12][lane<64][8] : leaf, K=256
// ---------------------------------------------------------------------------
__global__ __launch_bounds__(256)
void wt2_kernel(const float* __restrict__ W_iou, const float* __restrict__ U_iou,
                const float* __restrict__ U_f_w,
                short* __restrict__ Wt2I, short* __restrict__ Wt2L){
  int t = blockIdx.x*256 + threadIdx.x;
  if (blockIdx.x < 320){
    int lane = t & 63, rest = t >> 6;
    int nr = rest % 20; int rest2 = rest / 20;
    int kt = rest2 & 15, hhb = rest2 >> 4;
    int g = nr/5, strip = nr - g*5;
    int j = strip*256 + hhb*64 + g*16 + (lane&15);
    int k0 = kt*32 + (lane>>4)*8;
    const float* src = (j < 768) ? (U_iou + (i64)j*512 + k0)
                                 : (U_f_w + (i64)(j-768)*512 + k0);
    short* dst = Wt2I + (i64)t*8;
    #pragma unroll
    for (int e=0;e<8;e++) dst[e] = f2bf(src[e]);
  } else {
    int t2 = t - 320*256;
    int lane = t2 & 63, rest = t2 >> 6;
    int nr = rest % 12; int rest2 = rest / 12;
    int kt = rest2 & 7, hhb = rest2 >> 3;
    int g = nr/3, strip = nr - g*3;
    int j = strip*256 + hhb*64 + g*16 + (lane&15);
    int k0 = kt*32 + (lane>>4)*8;
    const float* src = W_iou + (i64)j*256 + k0;
    short* dst = Wt2L + (i64)t2*8;
    #pragma unroll
    for (int e=0;e<8;e++) dst[e] = f2bf(src[e]);
  }
}

// Gather+sum 5 embeddings per leaf -> bf16, stored into hb's LEAF rows.
__global__ __launch_bounds__(256)
void wemb_kernel(const int* __restrict__ wordid, const float* __restrict__ emb,
                 short* __restrict__ hb){
  int id = blockIdx.x*256 + threadIdx.x;
  int row = id >> 5, q = id & 31;
  int b = row >> 10, j = row & 1023;
  i64 n = (i64)b*Tn + LEAF0 + j;
  const int* wid = wordid + n*5;
  float s[8];
  #pragma unroll
  for (int e=0;e<8;e++) s[e] = 0.f;
  #pragma unroll
  for (int l=0;l<5;l++){
    const float* er = emb + (i64)wid[l]*Hd + q*8;
    float4 v0 = *(const float4*)(er);
    float4 v1 = *(const float4*)(er+4);
    s[0]+=v0.x; s[1]+=v0.y; s[2]+=v0.z; s[3]+=v0.w;
    s[4]+=v1.x; s[5]+=v1.y; s[6]+=v1.z; s[7]+=v1.w;
  }
  short o[8];
  #pragma unroll
  for (int e=0;e<8;e++) o[e] = f2bf(s[e]);
  *(short8v*)(hb + n*Hd + q*8) = *(short8v*)o;
}

// Convert leaf h (fp32 in d_out) -> bf16 hb rows.
__global__ __launch_bounds__(256)
void hconv_kernel(const float* __restrict__ hOut, short* __restrict__ hb){
  int id = blockIdx.x*256 + threadIdx.x;
  i64 idx = (i64)id*8;
  int row = (int)(idx >> 8), col = (int)(idx & 255);
  int b = row >> 10, j = row & 1023;
  i64 off = ((i64)b*Tn + LEAF0 + j)*Hd + col;
  const float* src = hOut + off;
  float4 v0 = *(const float4*)src;
  float4 v1 = *(const float4*)(src+4);
  short o[8] = { f2bf(v0.x),f2bf(v0.y),f2bf(v0.z),f2bf(v0.w),
                 f2bf(v1.x),f2bf(v1.y),f2bf(v1.z),f2bf(v1.w) };
  *(short8v*)(hb + off) = *(short8v*)o;
}

// ---------------------------------------------------------------------------
// Leaf GEMM: block 128 rows x 64 hcols x {i,o,u}. A: 5-deep LDS ring staged
// 3 ahead via global_load_lds; B: regs, double-buffered 1 ahead; counted vmcnt.
// ---------------------------------------------------------------------------
#define LEAF_ITER(KT, VM, BC, BN)                                            \
  {                                                                          \
    if ((KT)+1 < 8){                                                         \
      const short* bp = wbB + (i64)((KT)+1)*12*512;                          \
      _Pragma("unroll")                                                      \
      for (int s=0;s<3;s++) BN[s] = *(const short8v*)(bp + (i64)s*512);      \
    }                                                                        \
    asm volatile("" ::: "memory");                                           \
    if ((KT)+3 < 8) GL2LDS(srcA + ((KT)+3)*32, &As[((KT)+3)%5][w*512]);      \
    asm volatile("s_waitcnt vmcnt(" #VM ")" ::: "memory");                   \
    __builtin_amdgcn_s_barrier();                                            \
    short8v afr[4];                                                          \
    _Pragma("unroll")                                                        \
    for (int mr=0;mr<4;mr++)                                                 \
      afr[mr] = *(const short8v*)&As[(KT)%5][(wm*4+mr)*512 + lane*8];        \
    _Pragma("unroll")                                                        \
    for (int mr=0;mr<4;mr++)                                                 \
      _Pragma("unroll")                                                      \
      for (int s=0;s<3;s++)                                                  \
        acc[mr][s] = __builtin_amdgcn_mfma_f32_16x16x32_bf16(afr[mr], BC[s], acc[mr][s], 0, 0, 0); \
    asm volatile("s_waitcnt lgkmcnt(0)" ::: "memory");                       \
  }

__global__ __launch_bounds__(512)
void leaf_gemm(const short* __restrict__ hb, const short* __restrict__ WB,
               const float* __restrict__ b_iou, const float* __restrict__ c0,
               float* __restrict__ hOut, short* __restrict__ cbb){
  __shared__ __align__(16) short As[5][8*512];   // 40 KB
  const int tid = threadIdx.x;
  const int lane = tid & 63, w = tid >> 6;
  const int wm = w >> 2, wg = w & 3;
  const int m0 = blockIdx.x*128;
  const int hhb = blockIdx.y;

  const int rA = m0 + w*16 + (lane&15);
  const int bA = rA >> 10, jA = rA & 1023;
  const short* srcA = hb + ((i64)bA*Tn + LEAF0 + jA)*Hd + (lane>>4)*8;
  const short* wbB = WB + (i64)hhb*96*512 + (i64)(wg*3)*512 + lane*8;

  float4v acc[4][3];
  #pragma unroll
  for (int mr=0;mr<4;mr++)
    #pragma unroll
    for (int s=0;s<3;s++){ float4v z = {0.f,0.f,0.f,0.f}; acc[mr][s] = z; }

  short8v b0[3], b1[3];
  GL2LDS(srcA, &As[0][w*512]);
  GL2LDS(srcA + 32, &As[1][w*512]);
  GL2LDS(srcA + 64, &As[2][w*512]);
  asm volatile("" ::: "memory");
  #pragma unroll
  for (int s=0;s<3;s++) b0[s] = *(const short8v*)(wbB + (i64)s*512);

  LEAF_ITER(0,4,b0,b1)  LEAF_ITER(1,5,b1,b0)
  LEAF_ITER(2,5,b0,b1)  LEAF_ITER(3,5,b1,b0)
  LEAF_ITER(4,5,b0,b1)  LEAF_ITER(5,4,b1,b0)
  LEAF_ITER(6,3,b0,b1)  LEAF_ITER(7,0,b1,b0)

  const int hcol = hhb*64 + wg*16 + (lane&15);
  const float bi = b_iou[hcol], bo = b_iou[256+hcol], bu = b_iou[512+hcol];
  #pragma unroll
  for (int mr=0;mr<4;mr++){
    const int mgb = m0 + wm*64 + mr*16 + ((lane>>4)<<2);
    #pragma unroll
    for (int r=0;r<4;r++){
      const int m = mgb + r;
      const int b = m >> 10, j = m & 1023;
      const i64 n = (i64)b*Tn + LEAF0 + j;
      const float i_ = acc[mr][0][r] + bi;
      const float o_ = acc[mr][1][r] + bo;
      const float u_ = acc[mr][2][r] + bu;
      const float cn = sigm(i_)*ftanh(u_) + c0[n*Hd + hcol];
      cbb[n*Hd + hcol] = f2bf(cn);
      hOut[n*Hd + hcol] = sigm(o_)*ftanh(cn);
    }
  }
}

// ---------------------------------------------------------------------------
// Internal level: block 128 rows x 64 hcols x {i,o,u,fl,fr}. Same pipeline.
// ---------------------------------------------------------------------------
#define LVL_ITER(KT, VM, BC, BN)                                             \
  {                                                                          \
    if ((KT)+1 < 16){                                                        \
      const short* bp = wbB + (i64)((KT)+1)*20*512;                          \
      _Pragma("unroll")                                                      \
      for (int s=0;s<5;s++) BN[s] = *(const short8v*)(bp + (i64)s*512);      \
    }                                                                        \
    asm volatile("" ::: "memory");                                           \
    if ((KT)+3 < 16) GL2LDS(srcA + ((KT)+3)*32, &As[((KT)+3)%5][w*512]);     \
    asm volatile("s_waitcnt vmcnt(" #VM ")" ::: "memory");                   \
    __builtin_amdgcn_s_barrier();                                            \
    short8v afr[4];                                                          \
    _Pragma("unroll")                                                        \
    for (int mr=0;mr<4;mr++)                                                 \
      afr[mr] = *(const short8v*)&As[(KT)%5][(wm*4+mr)*512 + lane*8];        \
    _Pragma("unroll")                                                        \
    for (int mr=0;mr<4;mr++)                                                 \
      _Pragma("unroll")                                                      \
      for (int s=0;s<5;s++)                                                  \
        acc[mr][s] = __builtin_amdgcn_mfma_f32_16x16x32_bf16(afr[mr], BC[s], acc[mr][s], 0, 0, 0); \
    asm volatile("s_waitcnt lgkmcnt(0)" ::: "memory");                       \
  }

__global__ __launch_bounds__(512)
void level_gemm(const short* __restrict__ WB,
                const float* __restrict__ b_iou, const float* __restrict__ U_f_b,
                float* __restrict__ hOut, short* __restrict__ hb, short* __restrict__ cbb,
                float* __restrict__ outRoot, int s0, int e0, int logn){
  __shared__ __align__(16) short As[5][8*512];   // 40 KB
  const int tid = threadIdx.x;
  const int lane = tid & 63, w = tid >> 6;
  const int wm = w >> 2, wg = w & 3;
  const int m0 = blockIdx.x*128;
  const int hhb = blockIdx.y;
  const int Mtot = Bb << logn;
  const int nm1 = (1<<logn)-1;

  int rA = m0 + w*16 + (lane&15); if (rA >= Mtot) rA = Mtot-1;
  const int bA = rA >> logn, jA = rA & nm1;
  const short* srcA = hb + ((i64)bA*Tn + e0)*Hd + (i64)jA*512 + (lane>>4)*8;
  const short* wbB = WB + (i64)hhb*320*512 + (i64)(wg*5)*512 + lane*8;

  float4v acc[4][5];
  #pragma unroll
  for (int mr=0;mr<4;mr++)
    #pragma unroll
    for (int s=0;s<5;s++){ float4v z = {0.f,0.f,0.f,0.f}; acc[mr][s] = z; }

  short8v b0[5], b1[5];
  GL2LDS(srcA, &As[0][w*512]);
  GL2LDS(srcA + 32, &As[1][w*512]);
  GL2LDS(srcA + 64, &As[2][w*512]);
  asm volatile("" ::: "memory");
  #pragma unroll
  for (int s=0;s<5;s++) b0[s] = *(const short8v*)(wbB + (i64)s*512);

  LVL_ITER( 0,6,b0,b1)  LVL_ITER( 1,7,b1,b0)
  LVL_ITER( 2,7,b0,b1)  LVL_ITER( 3,7,b1,b0)
  LVL_ITER( 4,7,b0,b1)  LVL_ITER( 5,7,b1,b0)
  LVL_ITER( 6,7,b0,b1)  LVL_ITER( 7,7,b1,b0)
  LVL_ITER( 8,7,b0,b1)  LVL_ITER( 9,7,b1,b0)
  LVL_ITER(10,7,b0,b1)  LVL_ITER(11,7,b1,b0)
  LVL_ITER(12,7,b0,b1)  LVL_ITER(13,6,b1,b0)
  LVL_ITER(14,5,b0,b1)  LVL_ITER(15,0,b1,b0)

  const int hcol = hhb*64 + wg*16 + (lane&15);
  const float bi = b_iou[hcol], bo = b_iou[256+hcol], bu = b_iou[512+hcol];
  const float bfl = U_f_b[hcol], bfr2 = U_f_b[256+hcol];
  #pragma unroll
  for (int mr=0;mr<4;mr++){
    const int mgb = m0 + wm*64 + mr*16 + ((lane>>4)<<2);
    #pragma unroll
    for (int r=0;r<4;r++){
      const int m = mgb + r;
      if (m < Mtot){
        const int b = m >> logn, j = m & nm1;
        const i64 base = (i64)b*Tn;
        const i64 cidx = (base + e0 + 2*j)*Hd + hcol;
        const float cl = bf2f((unsigned short)cbb[cidx]);
        const float cr = bf2f((unsigned short)cbb[cidx + Hd]);
        const float i_ = acc[mr][0][r]+bi, o_ = acc[mr][1][r]+bo, u_ = acc[mr][2][r]+bu;
        const float fl = acc[mr][3][r]+bfl, fr = acc[mr][4][r]+bfr2;
        const float cn = sigm(i_)*ftanh(u_) + sigm(fl)*cl + sigm(fr)*cr;
        const float hv = sigm(o_)*ftanh(cn);
        const i64 oidx = (base + s0 + j)*Hd + hcol;
        cbb[oidx] = f2bf(cn);
        hb[oidx]  = f2bf(hv);
        hOut[oidx] = hv;
        if (s0 == 0){
          outRoot[b*Hd + hcol] = hv;
          outRoot[Bb*Hd + b*Hd + hcol] = cn;
        }
      }
    }
  }
}

extern "C" void kernel_launch(void* const* d_in, const int* in_sizes, int n_in,
                              void* d_out, int out_size, void* d_ws, size_t ws_size,
                              hipStream_t stream){
  const int*   wordid = (const int*)  d_in[0];
  const float* c0     = (const float*)d_in[3];
  const float* emb    = (const float*)d_in[6];
  const float* W_iou  = (const float*)d_in[7];
  const float* U_iou  = (const float*)d_in[8];
  const float* b_iou  = (const float*)d_in[9];
  const float* U_f_w  = (const float*)d_in[10];
  const float* U_f_b  = (const float*)d_in[11];

  float* hOut    = (float*)d_out;            // (B,T,H) fp32
  float* outRoot = hOut + NTH;               // root_h then root_c
  short* cbb  = (short*)d_ws;                // c  bf16 (B,T,H)
  short* hb   = cbb + NTH;                   // h  bf16 (B,T,H); leaf rows hold wemb pre-GEMM
  short* Wt2I = hb + NTH;                    // 655360 shorts
  short* Wt2L = Wt2I + 655360;               // 196608 shorts

  hipLaunchKernelGGL(wt2_kernel, dim3(416), dim3(256), 0, stream,
                     W_iou, U_iou, U_f_w, Wt2I, Wt2L);
  hipLaunchKernelGGL(wemb_kernel, dim3(8192), dim3(256), 0, stream, wordid, emb, hb);
  hipLaunchKernelGGL(leaf_gemm, dim3(512,4), dim3(512), 0, stream,
                     hb, Wt2L, b_iou, c0, hOut, cbb);
  hipLaunchKernelGGL(hconv_kernel, dim3(8192), dim3(256), 0, stream, hOut, hb);
  for (int d = 9; d >= 0; --d){
    const int n = 1<<d, s = n-1, e = 2*n-1;
    const int bm = (64*n + 127)/128;
    hipLaunchKernelGGL(level_gemm, dim3(bm < 1 ? 1 : bm, 4), dim3(512), 0, stream,
                       Wt2I, b_iou, U_f_b, hOut, hb, cbb, outRoot, s, e, d);
  }
}

// Round 7
// 400.535 us; speedup vs baseline: 1.3190x; 1.0888x over previous
//
#include <hip/hip_runtime.h>
#include <math.h>

typedef long long i64;
typedef short short8v __attribute__((ext_vector_type(8)));
typedef float float4v __attribute__((ext_vector_type(4)));

#define Hd 256
#define Bb 64
#define Tn 2047
#define LEAF0 1023
#define NTH 33538048LL   // B*T*H elements

__device__ __forceinline__ float frcp(float x){ return __builtin_amdgcn_rcpf(x); }
__device__ __forceinline__ float sigm(float x){ return frcp(1.0f+__expf(-x)); }
__device__ __forceinline__ float ftanh(float x){ return 1.0f - 2.0f*frcp(__expf(2.0f*x)+1.0f); }
__device__ __forceinline__ float bf2f(unsigned short s){
  union { unsigned u; float f; } v; v.u = ((unsigned)s)<<16; return v.f; }
__device__ __forceinline__ short f2bf(float f){
  union { float f; unsigned u; } v; v.f = f;
  unsigned r = v.u + 0x7FFF + ((v.u>>16)&1);
  return (short)(r>>16); }

#define GL2LDS(gp, lp) __builtin_amdgcn_global_load_lds( \
  (const __attribute__((address_space(1))) void*)(gp), \
  (__attribute__((address_space(3))) void*)(lp), 16, 0, 0)

// ---------------------------------------------------------------------------
// Pack weights to bf16 in MFMA fragment order.
// Wt2I[hhb][kt<16][nr<20][lane<64][8] : levels, K=512
// Wt2L[hhb][kt<8][nr<12][lane<64][8] : leaf, K=256
// ---------------------------------------------------------------------------
__global__ __launch_bounds__(256)
void wt2_kernel(const float* __restrict__ W_iou, const float* __restrict__ U_iou,
                const float* __restrict__ U_f_w,
                short* __restrict__ Wt2I, short* __restrict__ Wt2L){
  int t = blockIdx.x*256 + threadIdx.x;
  if (blockIdx.x < 320){
    int lane = t & 63, rest = t >> 6;
    int nr = rest % 20; int rest2 = rest / 20;
    int kt = rest2 & 15, hhb = rest2 >> 4;
    int g = nr/5, strip = nr - g*5;
    int j = strip*256 + hhb*64 + g*16 + (lane&15);
    int k0 = kt*32 + (lane>>4)*8;
    const float* src = (j < 768) ? (U_iou + (i64)j*512 + k0)
                                 : (U_f_w + (i64)(j-768)*512 + k0);
    short* dst = Wt2I + (i64)t*8;
    #pragma unroll
    for (int e=0;e<8;e++) dst[e] = f2bf(src[e]);
  } else {
    int t2 = t - 320*256;
    int lane = t2 & 63, rest = t2 >> 6;
    int nr = rest % 12; int rest2 = rest / 12;
    int kt = rest2 & 7, hhb = rest2 >> 3;
    int g = nr/3, strip = nr - g*3;
    int j = strip*256 + hhb*64 + g*16 + (lane&15);
    int k0 = kt*32 + (lane>>4)*8;
    const float* src = W_iou + (i64)j*256 + k0;
    short* dst = Wt2L + (i64)t2*8;
    #pragma unroll
    for (int e=0;e<8;e++) dst[e] = f2bf(src[e]);
  }
}

// Gather+sum 5 embeddings per leaf -> bf16, into OVERLAY region:
// leaf j<1023 -> hb internal row (b*Tn + j); j==1023 -> cbb root row (b*Tn).
__global__ __launch_bounds__(256)
void wemb_kernel(const int* __restrict__ wordid, const float* __restrict__ emb,
                 short* __restrict__ hb, short* __restrict__ cbb){
  int id = blockIdx.x*256 + threadIdx.x;
  int row = id >> 5, q = id & 31;
  int b = row >> 10, j = row & 1023;
  i64 tb = (i64)b*Tn;
  const int* wid = wordid + (tb + LEAF0 + j)*5;
  float s[8];
  #pragma unroll
  for (int e=0;e<8;e++) s[e] = 0.f;
  #pragma unroll
  for (int l=0;l<5;l++){
    const float* er = emb + (i64)wid[l]*Hd + q*8;
    float4 v0 = *(const float4*)(er);
    float4 v1 = *(const float4*)(er+4);
    s[0]+=v0.x; s[1]+=v0.y; s[2]+=v0.z; s[3]+=v0.w;
    s[4]+=v1.x; s[5]+=v1.y; s[6]+=v1.z; s[7]+=v1.w;
  }
  short o[8];
  #pragma unroll
  for (int e=0;e<8;e++) o[e] = f2bf(s[e]);
  short* dst = (j < 1023) ? (hb + (tb + j)*Hd) : (cbb + tb*Hd);
  *(short8v*)(dst + q*8) = *(short8v*)o;
}

// ---------------------------------------------------------------------------
// Leaf GEMM: block 128 rows x 64 hcols x {i,o,u}. A: ring-5 LDS, 3 ahead;
// B: regs triple-buffered, 2 ahead; exact counted vmcnt. Writes h to hOut
// (fp32) AND hb leaf rows (bf16) -- no separate hconv pass.
// ---------------------------------------------------------------------------
#define LEAF_ITER(KT, VM, BU, BL)                                            \
  {                                                                          \
    if ((KT)+2 < 8){                                                         \
      const short* bp = wbB + (i64)((KT)+2)*12*512;                          \
      _Pragma("unroll")                                                      \
      for (int s=0;s<3;s++) BL[s] = *(const short8v*)(bp + (i64)s*512);      \
    }                                                                        \
    asm volatile("" ::: "memory");                                           \
    if ((KT)+3 < 8) GL2LDS(srcA + ((KT)+3)*32, &As[((KT)+3)%5][w*512]);      \
    asm volatile("s_waitcnt vmcnt(" #VM ")" ::: "memory");                   \
    __builtin_amdgcn_s_barrier();                                            \
    asm volatile("" ::: "memory");                                           \
    short8v afr[4];                                                          \
    _Pragma("unroll")                                                        \
    for (int mr=0;mr<4;mr++)                                                 \
      afr[mr] = *(const short8v*)&As[(KT)%5][(wm*4+mr)*512 + lane*8];        \
    _Pragma("unroll")                                                        \
    for (int mr=0;mr<4;mr++)                                                 \
      _Pragma("unroll")                                                      \
      for (int s=0;s<3;s++)                                                  \
        acc[mr][s] = __builtin_amdgcn_mfma_f32_16x16x32_bf16(afr[mr], BU[s], acc[mr][s], 0, 0, 0); \
    asm volatile("s_waitcnt lgkmcnt(0)" ::: "memory");                       \
  }

__global__ __launch_bounds__(512)
void leaf_gemm(const short* __restrict__ hb, const short* __restrict__ cbb,
               const short* __restrict__ WB,
               const float* __restrict__ b_iou, const float* __restrict__ c0,
               float* __restrict__ hOut, short* __restrict__ hbOut,
               short* __restrict__ cbbOut){
  __shared__ __align__(16) short As[5][8*512];   // 40 KB
  const int tid = threadIdx.x;
  const int lane = tid & 63, w = tid >> 6;
  const int wm = w >> 2, wg = w & 3;
  const int m0 = blockIdx.x*128;
  const int hhb = blockIdx.y;

  const int rA = m0 + w*16 + (lane&15);
  const int bA = rA >> 10, jA = rA & 1023;
  const short* baseA = (jA < 1023) ? (hb + ((i64)bA*Tn + jA)*Hd)
                                   : (cbb + (i64)bA*Tn*Hd);
  const short* srcA = baseA + (lane>>4)*8;
  const short* wbB = WB + (i64)hhb*96*512 + (i64)(wg*3)*512 + lane*8;

  float4v acc[4][3];
  #pragma unroll
  for (int mr=0;mr<4;mr++)
    #pragma unroll
    for (int s=0;s<3;s++){ float4v z = {0.f,0.f,0.f,0.f}; acc[mr][s] = z; }

  short8v b0[3], b1[3], b2[3];
  #pragma unroll
  for (int s=0;s<3;s++) b0[s] = *(const short8v*)(wbB + (i64)s*512);
  asm volatile("" ::: "memory");
  GL2LDS(srcA, &As[0][w*512]);
  GL2LDS(srcA + 32, &As[1][w*512]);
  GL2LDS(srcA + 64, &As[2][w*512]);
  asm volatile("" ::: "memory");
  #pragma unroll
  for (int s=0;s<3;s++) b1[s] = *(const short8v*)(wbB + (i64)(12+s)*512);
  asm volatile("" ::: "memory");

  LEAF_ITER(0,9,b0,b2)  LEAF_ITER(1,8,b1,b0)
  LEAF_ITER(2,9,b2,b1)  LEAF_ITER(3,9,b0,b2)
  LEAF_ITER(4,9,b1,b0)  LEAF_ITER(5,8,b2,b1)
  LEAF_ITER(6,4,b0,b2)  LEAF_ITER(7,0,b1,b0)

  const int hcol = hhb*64 + wg*16 + (lane&15);
  const float bi = b_iou[hcol], bo = b_iou[256+hcol], bu = b_iou[512+hcol];
  #pragma unroll
  for (int mr=0;mr<4;mr++){
    const int mgb = m0 + wm*64 + mr*16 + ((lane>>4)<<2);
    #pragma unroll
    for (int r=0;r<4;r++){
      const int m = mgb + r;
      const int b = m >> 10, j = m & 1023;
      const i64 n = (i64)b*Tn + LEAF0 + j;
      const float i_ = acc[mr][0][r] + bi;
      const float o_ = acc[mr][1][r] + bo;
      const float u_ = acc[mr][2][r] + bu;
      const float cn = sigm(i_)*ftanh(u_) + c0[n*Hd + hcol];
      const float hv = sigm(o_)*ftanh(cn);
      cbbOut[n*Hd + hcol] = f2bf(cn);
      hbOut[n*Hd + hcol]  = f2bf(hv);
      hOut[n*Hd + hcol] = hv;
    }
  }
}

// ---------------------------------------------------------------------------
// Internal level (d=9..6): block 128 rows x 64 hcols x {i,o,u,fl,fr}.
// A: ring-5 LDS 3 ahead; B: regs triple-buffered 2 ahead; counted vmcnt.
// ---------------------------------------------------------------------------
#define LVL_ITER(KT, VM, BU, BL)                                             \
  {                                                                          \
    if ((KT)+2 < 16){                                                        \
      const short* bp = wbB + (i64)((KT)+2)*20*512;                          \
      _Pragma("unroll")                                                      \
      for (int s=0;s<5;s++) BL[s] = *(const short8v*)(bp + (i64)s*512);      \
    }                                                                        \
    asm volatile("" ::: "memory");                                           \
    if ((KT)+3 < 16) GL2LDS(srcA + ((KT)+3)*32, &As[((KT)+3)%5][w*512]);     \
    asm volatile("s_waitcnt vmcnt(" #VM ")" ::: "memory");                   \
    __builtin_amdgcn_s_barrier();                                            \
    asm volatile("" ::: "memory");                                           \
    short8v afr[4];                                                          \
    _Pragma("unroll")                                                        \
    for (int mr=0;mr<4;mr++)                                                 \
      afr[mr] = *(const short8v*)&As[(KT)%5][(wm*4+mr)*512 + lane*8];        \
    _Pragma("unroll")                                                        \
    for (int mr=0;mr<4;mr++)                                                 \
      _Pragma("unroll")                                                      \
      for (int s=0;s<5;s++)                                                  \
        acc[mr][s] = __builtin_amdgcn_mfma_f32_16x16x32_bf16(afr[mr], BU[s], acc[mr][s], 0, 0, 0); \
    asm volatile("s_waitcnt lgkmcnt(0)" ::: "memory");                       \
  }

__global__ __launch_bounds__(512)
void level_gemm(const short* __restrict__ WB,
                const float* __restrict__ b_iou, const float* __restrict__ U_f_b,
                float* __restrict__ hOut, short* __restrict__ hb, short* __restrict__ cbb,
                int s0, int e0, int logn){
  __shared__ __align__(16) short As[5][8*512];   // 40 KB
  const int tid = threadIdx.x;
  const int lane = tid & 63, w = tid >> 6;
  const int wm = w >> 2, wg = w & 3;
  const int m0 = blockIdx.x*128;
  const int hhb = blockIdx.y;
  const int nm1 = (1<<logn)-1;

  const int rA = m0 + w*16 + (lane&15);
  const int bA = rA >> logn, jA = rA & nm1;
  const short* srcA = hb + ((i64)bA*Tn + e0)*Hd + (i64)jA*512 + (lane>>4)*8;
  const short* wbB = WB + (i64)hhb*320*512 + (i64)(wg*5)*512 + lane*8;

  float4v acc[4][5];
  #pragma unroll
  for (int mr=0;mr<4;mr++)
    #pragma unroll
    for (int s=0;s<5;s++){ float4v z = {0.f,0.f,0.f,0.f}; acc[mr][s] = z; }

  short8v b0[5], b1[5], b2[5];
  #pragma unroll
  for (int s=0;s<5;s++) b0[s] = *(const short8v*)(wbB + (i64)s*512);
  asm volatile("" ::: "memory");
  GL2LDS(srcA, &As[0][w*512]);
  GL2LDS(srcA + 32, &As[1][w*512]);
  GL2LDS(srcA + 64, &As[2][w*512]);
  asm volatile("" ::: "memory");
  #pragma unroll
  for (int s=0;s<5;s++) b1[s] = *(const short8v*)(wbB + (i64)(20+s)*512);
  asm volatile("" ::: "memory");

  LVL_ITER( 0,13,b0,b2)  LVL_ITER( 1,12,b1,b0)  LVL_ITER( 2,13,b2,b1)
  LVL_ITER( 3,13,b0,b2)  LVL_ITER( 4,13,b1,b0)  LVL_ITER( 5,13,b2,b1)
  LVL_ITER( 6,13,b0,b2)  LVL_ITER( 7,13,b1,b0)  LVL_ITER( 8,13,b2,b1)
  LVL_ITER( 9,13,b0,b2)  LVL_ITER(10,13,b1,b0)  LVL_ITER(11,13,b2,b1)
  LVL_ITER(12,13,b0,b2)  LVL_ITER(13,12,b1,b0)  LVL_ITER(14, 6,b2,b1)
  LVL_ITER(15, 0,b0,b2)

  const int hcol = hhb*64 + wg*16 + (lane&15);
  const float bi = b_iou[hcol], bo = b_iou[256+hcol], bu = b_iou[512+hcol];
  const float bfl = U_f_b[hcol], bfr2 = U_f_b[256+hcol];
  #pragma unroll
  for (int mr=0;mr<4;mr++){
    const int mgb = m0 + wm*64 + mr*16 + ((lane>>4)<<2);
    #pragma unroll
    for (int r=0;r<4;r++){
      const int m = mgb + r;
      const int b = m >> logn, j = m & nm1;
      const i64 base = (i64)b*Tn;
      const i64 cidx = (base + e0 + 2*j)*Hd + hcol;
      const float cl = bf2f((unsigned short)cbb[cidx]);
      const float cr = bf2f((unsigned short)cbb[cidx + Hd]);
      const float i_ = acc[mr][0][r]+bi, o_ = acc[mr][1][r]+bo, u_ = acc[mr][2][r]+bu;
      const float fl = acc[mr][3][r]+bfl, fr = acc[mr][4][r]+bfr2;
      const float cn = sigm(i_)*ftanh(u_) + sigm(fl)*cl + sigm(fr)*cr;
      const float hv = sigm(o_)*ftanh(cn);
      const i64 oidx = (base + s0 + j)*Hd + hcol;
      cbb[oidx] = f2bf(cn);
      hb[oidx]  = f2bf(hv);
      hOut[oidx] = hv;
    }
  }
}

// ---------------------------------------------------------------------------
// Fused small levels d=5..0: one block per tree. Children h/c live in
// XOR-swizzled LDS; B from L2 registers; one __syncthreads per level.
// ---------------------------------------------------------------------------
__global__ __launch_bounds__(512)
void tree_fused(const short* __restrict__ WB, const float* __restrict__ b_iou,
                const float* __restrict__ U_f_b, float* __restrict__ hOut,
                const short* __restrict__ hb, const short* __restrict__ cbb,
                float* __restrict__ outRoot){
  __shared__ __align__(16) short BUF[192*256];   // 96 KB
  short* L0H = BUF;             // 64 rows
  short* L0C = BUF + 64*256;    // 64 rows
  short* L1H = BUF + 128*256;   // 32 rows
  short* L1C = BUF + 160*256;   // 32 rows
  const int tid = threadIdx.x;
  const int lane = tid & 63, w = tid >> 6;
  const int wm = w >> 2, wg = w & 3;
  const int b = blockIdx.x;
  const i64 tb = (i64)b*Tn;

  // stage level-6 h,c (tree rows 63..126) into L0 with XOR swizzle
  #pragma unroll
  for (int p=0;p<4;p++){
    int idx = p*512 + tid;
    int row = idx >> 5, ch = idx & 31;
    int doff = ((row*256 + ch*8)*2) ^ ((row&7)<<4);
    short8v vh = *(const short8v*)(hb  + (tb + 63 + row)*Hd + ch*8);
    short8v vc = *(const short8v*)(cbb + (tb + 63 + row)*Hd + ch*8);
    *(short8v*)((char*)L0H + doff) = vh;
    *(short8v*)((char*)L0C + doff) = vc;
  }
  __syncthreads();

  short* inH = L0H; short* inC = L0C; short* outH = L1H; short* outC = L1C;

  for (int d = 5; d >= 0; --d){
    const int M = 1<<d, s0 = M-1;
    if (wm == 0 || d == 5){
      const int mg = (d == 5) ? wm*16 : 0;
      int j = mg + (lane&15); if (j > s0) j = s0;
      const int k0b = (lane>>4)*8;
      for (int hhb = 0; hhb < 4; ++hhb){
        float4v acc[5];
        #pragma unroll
        for (int s=0;s<5;s++){ float4v z = {0.f,0.f,0.f,0.f}; acc[s] = z; }
        const short* wbB = WB + (i64)hhb*320*512 + (i64)(wg*5)*512 + lane*8;
        #pragma unroll
        for (int kt=0; kt<16; ++kt){
          const int k0 = kt*32 + k0b;
          const int crow = 2*j + (k0>>8), ccol = k0 & 255;
          const int aoff = ((crow*256 + ccol)*2) ^ ((crow&7)<<4);
          short8v a = *(const short8v*)((const char*)inH + aoff);
          const short* bp = wbB + (i64)kt*20*512;
          #pragma unroll
          for (int s=0;s<5;s++){
            short8v bb = *(const short8v*)(bp + (i64)s*512);
            acc[s] = __builtin_amdgcn_mfma_f32_16x16x32_bf16(a, bb, acc[s], 0, 0, 0);
          }
        }
        const int hcol = hhb*64 + wg*16 + (lane&15);
        const float bi = b_iou[hcol], bo = b_iou[256+hcol], bu = b_iou[512+hcol];
        const float bfl = U_f_b[hcol], bfr2 = U_f_b[256+hcol];
        #pragma unroll
        for (int r=0;r<4;r++){
          const int row = mg + ((lane>>4)<<2) + r;
          if (row < M){
            const int c0r = 2*row, c1r = 2*row+1;
            const float cl = bf2f(*(const unsigned short*)((const char*)inC +
                              (((c0r*256 + hcol)*2) ^ ((c0r&7)<<4))));
            const float cr = bf2f(*(const unsigned short*)((const char*)inC +
                              (((c1r*256 + hcol)*2) ^ ((c1r&7)<<4))));
            const float i_ = acc[0][r]+bi, o_ = acc[1][r]+bo, u_ = acc[2][r]+bu;
            const float fl = acc[3][r]+bfl, fr = acc[4][r]+bfr2;
            const float cn = sigm(i_)*ftanh(u_) + sigm(fl)*cl + sigm(fr)*cr;
            const float hv = sigm(o_)*ftanh(cn);
            const int ooff = ((row*256 + hcol)*2) ^ ((row&7)<<4);
            *(short*)((char*)outH + ooff) = f2bf(hv);
            *(short*)((char*)outC + ooff) = f2bf(cn);
            hOut[(tb + s0 + row)*Hd + hcol] = hv;
            if (d == 0){
              outRoot[b*Hd + hcol] = hv;
              outRoot[Bb*Hd + b*Hd + hcol] = cn;
            }
          }
        }
      }
    }
    __syncthreads();
    short* t;
    t = inH; inH = outH; outH = t;
    t = inC; inC = outC; outC = t;
  }
}

extern "C" void kernel_launch(void* const* d_in, const int* in_sizes, int n_in,
                              void* d_out, int out_size, void* d_ws, size_t ws_size,
                              hipStream_t stream){
  const int*   wordid = (const int*)  d_in[0];
  const float* c0     = (const float*)d_in[3];
  const float* emb    = (const float*)d_in[6];
  const float* W_iou  = (const float*)d_in[7];
  const float* U_iou  = (const float*)d_in[8];
  const float* b_iou  = (const float*)d_in[9];
  const float* U_f_w  = (const float*)d_in[10];
  const float* U_f_b  = (const float*)d_in[11];

  float* hOut    = (float*)d_out;            // (B,T,H) fp32
  float* outRoot = hOut + NTH;               // root_h then root_c
  short* cbb  = (short*)d_ws;                // c bf16 (B,T,H); root rows hold wemb overlay
  short* hb   = cbb + NTH;                   // h bf16 (B,T,H); internal rows hold wemb overlay pre-leaf
  short* Wt2I = hb + NTH;                    // 655360 shorts
  short* Wt2L = Wt2I + 655360;               // 196608 shorts

  hipLaunchKernelGGL(wt2_kernel, dim3(416), dim3(256), 0, stream,
                     W_iou, U_iou, U_f_w, Wt2I, Wt2L);
  hipLaunchKernelGGL(wemb_kernel, dim3(8192), dim3(256), 0, stream,
                     wordid, emb, hb, cbb);
  hipLaunchKernelGGL(leaf_gemm, dim3(512,4), dim3(512), 0, stream,
                     hb, cbb, Wt2L, b_iou, c0, hOut, hb, cbb);
  for (int d = 9; d >= 6; --d){
    const int n = 1<<d, s = n-1, e = 2*n-1;
    const int bm = (64*n + 127)/128;
    hipLaunchKernelGGL(level_gemm, dim3(bm,4), dim3(512), 0, stream,
                       Wt2I, b_iou, U_f_b, hOut, hb, cbb, s, e, d);
  }
  hipLaunchKernelGGL(tree_fused, dim3(64), dim3(512), 0, stream,
                     Wt2I, b_iou, U_f_b, hOut, hb, cbb, outRoot);
}